// Round 7
// baseline (465.391 us; speedup 1.0000x reference)
//
#include <hip/hip_runtime.h>
#include <stddef.h>

// out[n,j,h,w] = sum_{k,i} x[n,i,(h+55)%56, srccol(k,w)] * w[j,k,i]
// R7 = MEASUREMENT ROUND #2. Body = R3 (best measured, 303.0us total, conv
// ~50us inferred), wrapped in a 5x rep loop INSIDE one dispatch (idempotent:
// each rep recomputes+rewrites identical output; barrier between reps).
// Purpose: conv has never appeared in the top-5 counter table (fills at
// ~122us own all slots). At ~250us this dispatch lands in slot #1 and we
// finally read FETCH/WRITE/VALUBusy/MfmaUtil/Occupancy/bank-conflicts for
// conv itself. R6 established warm==cold==50us, which is ambiguous between
// (a) BW-bound at ~5.1TB/s pattern ceiling (L3 eff BW ~= HBM for this
// pattern) and (b) non-BW pipe pinning. This round's counters decide.

#define C_IN   128
#define C_OUT  32
#define HH     56
#define WW     56
#define HW     3136
#define KTOT   384
#define WSTRIDE 392              // padded K-stride for weights (bf16 elems)
#define XSTRIDE 136              // ushorts per col (272B = 17x16B -> bank-balanced b128 reads)
#define XROWSZ (57 * XSTRIDE)    // one source row: 56 real cols + zero col 56
#define NREP   5                 // measurement repeats inside one dispatch

typedef short bf16x8 __attribute__((ext_vector_type(8)));
typedef float f32x4  __attribute__((ext_vector_type(4)));
typedef float f32x4v __attribute__((ext_vector_type(4)));

static __device__ __forceinline__ unsigned short f2b(float f) {
    unsigned u = __builtin_bit_cast(unsigned, f);
    unsigned r = u + 0x7FFFu + ((u >> 16) & 1u);   // RNE
    return (unsigned short)(r >> 16);
}

static __device__ __forceinline__ unsigned pk2(float lo, float hi) {
    unsigned r;
    asm("v_cvt_pk_bf16_f32 %0, %1, %2" : "=v"(r) : "v"(lo), "v"(hi));  // RNE
    return r;
}

__global__ void pack_w_kernel(const float* __restrict__ w, unsigned short* __restrict__ ws) {
    int idx = blockIdx.x * 256 + threadIdx.x;
    if (idx < C_OUT * WSTRIDE) {
        int j = idx / WSTRIDE;
        int r = idx % WSTRIDE;
        ws[idx] = f2b(r < KTOT ? w[j * KTOT + r] : 0.0f);
    }
}

__global__ __launch_bounds__(512, 4)
void conv_mfma_kernel(const float* __restrict__ x, const unsigned short* __restrict__ ws,
                      float* __restrict__ out) {
    const int bid  = blockIdx.x;
    const int n    = bid / (HH / 4);
    const int h0   = (bid % (HH / 4)) * 4;
    const int tid  = threadIdx.x;
    const int lane = tid & 63;
    const int grp  = tid >> 6;           // 0..7

    // XT[src row r (0..3)][col 0..56][ch] bf16; col 56 = zeros
    __shared__ __align__(16) unsigned short XT[4 * XROWSZ];   // 62016 B

    // zero col 56 of all 4 rows: 4*136 ushorts = 1088 B = 68 uint4
    if (tid < 68) {
        int r = tid / 17, off = (tid % 17) * 8;
        *(uint4*)&XT[r * XROWSZ + WW * XSTRIDE + off] = make_uint4(0, 0, 0, 0);
    }

    const float* xb = x + (size_t)n * (C_IN * HW);

    // ---- invariant per-lane geometry (hoisted out of rep loop) ----
    const int q  = lane;
    const int rsrc = q / 14;
    const int c4 = q % 14;
    const int hs = (h0 + 55 + rsrc) % HH;
    const float* src0 = xb + (size_t)hs * WW + c4 * 4;
    unsigned short* dstc = &XT[rsrc * XROWSZ + (c4 * 4) * XSTRIDE];

    const int l15 = lane & 15;
    const int kb  = (lane >> 4) * 8;
    const int rr  = grp >> 1;
    const int hf  = grp & 1;
    const unsigned short* Xr = &XT[rr * XROWSZ];

    const unsigned short* bp[2][3];
#pragma unroll
    for (int ct2 = 0; ct2 < 2; ++ct2) {
        const int nn = (hf * 2 + ct2) * 16 + l15;
        const int cc0 = (nn >= 1 && nn <= 55) ? (nn + 54) % WW : WW;
        const int cc1 = (nn <= 55) ? (nn + 55) % WW : WW;
        const int cc2 = (nn <= 54) ? nn : WW;
        bp[ct2][0] = Xr + cc0 * XSTRIDE + kb;
        bp[ct2][1] = Xr + cc1 * XSTRIDE + kb;
        bp[ct2][2] = Xr + cc2 * XSTRIDE + kb;
    }

    const unsigned short* wp = ws + l15 * WSTRIDE + kb;
    const int j0 = (lane >> 4) * 4;
    float* ob = out + (size_t)n * (C_OUT * HW) + (size_t)(h0 + rr) * WW;

#pragma unroll 1
    for (int rep = 0; rep < NREP; ++rep) {
        // ---- stage 4 source rows (identical data every rep) ----
        if (q < WW) {
#pragma unroll
            for (int p = 0; p < 2; ++p) {
                const int ch0 = p * 64 + grp * 8;
                f32x4v v[8];
#pragma unroll
                for (int cc = 0; cc < 8; ++cc)
                    v[cc] = *(const f32x4v*)(src0 + (size_t)(ch0 + cc) * HW);
#pragma unroll
                for (int vc = 0; vc < 4; ++vc) {
                    uint4 w128;
                    w128.x = pk2(v[0][vc], v[1][vc]);
                    w128.y = pk2(v[2][vc], v[3][vc]);
                    w128.z = pk2(v[4][vc], v[5][vc]);
                    w128.w = pk2(v[6][vc], v[7][vc]);
                    *(uint4*)(dstc + vc * XSTRIDE + ch0) = w128;
                }
            }
        }
        __syncthreads();

        // ---- MFMA ----
        f32x4 acc[2][2];
#pragma unroll
        for (int ct2 = 0; ct2 < 2; ++ct2) {
            acc[ct2][0] = (f32x4){0.f, 0.f, 0.f, 0.f};
            acc[ct2][1] = (f32x4){0.f, 0.f, 0.f, 0.f};
        }

#pragma unroll
        for (int c = 0; c < 12; ++c) {
            const int tap = c >> 2;
            const int ib  = (c & 3) * 32;
            bf16x8 A0 = *(const bf16x8*)(wp + c * 32);
            bf16x8 A1 = *(const bf16x8*)(wp + 16 * WSTRIDE + c * 32);
#pragma unroll
            for (int ct2 = 0; ct2 < 2; ++ct2) {
                bf16x8 B = *(const bf16x8*)(bp[ct2][tap] + ib);
                acc[ct2][0] = __builtin_amdgcn_mfma_f32_16x16x32_bf16(A0, B, acc[ct2][0], 0, 0, 0);
                acc[ct2][1] = __builtin_amdgcn_mfma_f32_16x16x32_bf16(A1, B, acc[ct2][1], 0, 0, 0);
            }
        }

        // ---- epilogue ----
#pragma unroll
        for (int ct2 = 0; ct2 < 2; ++ct2) {
            const int nn = (hf * 2 + ct2) * 16 + l15;
            if (nn < WW) {
#pragma unroll
                for (int r = 0; r < 4; ++r) {
                    ob[(size_t)(j0 + r) * HW + nn]      = acc[ct2][0][r];
                    ob[(size_t)(j0 + r + 16) * HW + nn] = acc[ct2][1][r];
                }
            }
        }
        __syncthreads();   // all reads of XT done before next rep restages
    }
}

extern "C" void kernel_launch(void* const* d_in, const int* in_sizes, int n_in,
                              void* d_out, int out_size, void* d_ws, size_t ws_size,
                              hipStream_t stream) {
    const float* x = (const float*)d_in[0];
    const float* w = (const float*)d_in[1];
    float* out = (float*)d_out;
    unsigned short* ws = (unsigned short*)d_ws;   // 32*392*2 = 25088 B needed

    pack_w_kernel<<<(C_OUT * WSTRIDE + 255) / 256, 256, 0, stream>>>(w, ws);
    conv_mfma_kernel<<<dim3(128 * (HH / 4)), dim3(512), 0, stream>>>(x, ws, out);
}

// Round 8
// 311.695 us; speedup vs baseline: 1.4931x; 1.4931x over previous
//
#include <hip/hip_runtime.h>
#include <stddef.h>

// out[n,j,h,w] = sum_{k,i} x[n,i,(h+55)%56, srccol(k,w)] * w[j,k,i]
//   tap k=0: valid w>=1,  col (w+54)%56
//   tap k=1: always,      col (w+55)%56
//   tap k=2: valid w<=54, col w
// R8: BARRIER-FREE wave-per-row redesign. R7's 5-rep counters: MfmaUtil 8.5%,
// VALUBusy 4.9%, HBM 42%, occ 43% -> latency/phase-bound: the stage->sync->
// compute lockstep idles HBM ~30% of each block-round. Key fact: H is a ROLL
// not a conv -> output row h needs exactly ONE source row (h+55)%56. So:
// block = 64 threads = 1 wave = 1 output row. Wave stages its own source row
// (56 cols x 128 ch) into its PRIVATE 15.5KB LDS row, waits lgkmcnt (own
// writes), computes 96 MFMA, stores. NO __syncthreads anywhere. 10 blocks/CU
// free-run -> staging of some waves always overlaps compute of others ->
// HBM duty ~continuous. Grid 7168 = 128 n x 56 h, XCD-chunked (bijective:
// 7168%8==0) so adjacent h-rows share L2 lines within an XCD.

#define C_IN   128
#define C_OUT  32
#define HH     56
#define WW     56
#define HW     3136
#define KTOT   384
#define WSTRIDE 392              // padded K-stride for weights (bf16 elems)
#define XSTRIDE 136              // ushorts per col (272B = 17x16B -> bank-balanced b128 reads)
#define XROWSZ (57 * XSTRIDE)    // one source row: 56 real cols + zero col 56 (15504 B)

typedef short bf16x8 __attribute__((ext_vector_type(8)));
typedef float f32x4  __attribute__((ext_vector_type(4)));

static __device__ __forceinline__ unsigned short f2b(float f) {
    unsigned u = __builtin_bit_cast(unsigned, f);
    unsigned r = u + 0x7FFFu + ((u >> 16) & 1u);   // RNE
    return (unsigned short)(r >> 16);
}

static __device__ __forceinline__ unsigned pk2(float lo, float hi) {
    unsigned r;
    asm("v_cvt_pk_bf16_f32 %0, %1, %2" : "=v"(r) : "v"(lo), "v"(hi));  // RNE
    return r;
}

__global__ void pack_w_kernel(const float* __restrict__ w, unsigned short* __restrict__ ws) {
    int idx = blockIdx.x * 256 + threadIdx.x;
    if (idx < C_OUT * WSTRIDE) {
        int j = idx / WSTRIDE;
        int r = idx % WSTRIDE;
        ws[idx] = f2b(r < KTOT ? w[j * KTOT + r] : 0.0f);
    }
}

__global__ __launch_bounds__(64, 4)
void conv_mfma_kernel(const float* __restrict__ x, const unsigned short* __restrict__ ws,
                      float* __restrict__ out) {
    // XCD-chunked bijective swizzle: 7168 blocks = 8 XCDs x 896 contiguous wgs
    const int bid = blockIdx.x;
    const int wg  = (bid & 7) * 896 + (bid >> 3);
    const int n   = wg / HH;
    const int h   = wg % HH;               // this wave's output row
    const int hs  = (h + HH - 1) % HH;     // its single source row
    const int lane = threadIdx.x;

    // private source-row buffer: [col 0..56][ch 0..127] bf16; col 56 = zeros
    __shared__ __align__(16) unsigned short XT[XROWSZ];   // 15504 B

    // zero col 56: 136 ushorts = 17 uint4 (own wave, no sync needed)
    if (lane < 17) *(uint4*)&XT[WW * XSTRIDE + lane * 8] = make_uint4(0, 0, 0, 0);

    // ---- stage own source row: lane<56 -> (c4 = lane%14, chsub = lane/14) ----
    // instr (p,k): ch = p*32 + chsub*8 + k. Per instr: 4 segments of 224B
    // (14 lanes x float4 contiguous per chsub). 32 loads total, high MLP.
    {
        const int c4    = lane % 14;
        const int chsub = lane / 14;
        const float* sbase = x + (size_t)n * (C_IN * HW) + (size_t)hs * WW + c4 * 4
                               + (size_t)(chsub * 8) * HW;
        if (lane < WW) {
#pragma unroll
            for (int p = 0; p < 4; ++p) {
                f32x4 v[8];
#pragma unroll
                for (int k = 0; k < 8; ++k)
                    v[k] = *(const f32x4*)(sbase + (size_t)(p * 32 + k) * HW);
                const int chb = p * 32 + chsub * 8;
#pragma unroll
                for (int vc = 0; vc < 4; ++vc) {
                    uint4 w128;
                    w128.x = pk2(v[0][vc], v[1][vc]);
                    w128.y = pk2(v[2][vc], v[3][vc]);
                    w128.z = pk2(v[4][vc], v[5][vc]);
                    w128.w = pk2(v[6][vc], v[7][vc]);
                    *(uint4*)&XT[(c4 * 4 + vc) * XSTRIDE + chb] = w128;
                }
            }
        }
    }
    // own-wave LDS ordering: all stage writes visible before B-reads
    asm volatile("s_waitcnt lgkmcnt(0)" ::: "memory");

    // ---- compute: this wave does all 56 cols x 32 j of output row h ----
    const int l15 = lane & 15;
    const int kb  = (lane >> 4) * 8;

    const unsigned short* bp[4][3];
#pragma unroll
    for (int ct = 0; ct < 4; ++ct) {
        const int nn = ct * 16 + l15;
        const int cc0 = (nn >= 1 && nn <= 55) ? (nn + 54) % WW : WW;
        const int cc1 = (nn <= 55) ? (nn + 55) % WW : WW;
        const int cc2 = (nn <= 54) ? nn : WW;
        bp[ct][0] = XT + cc0 * XSTRIDE + kb;
        bp[ct][1] = XT + cc1 * XSTRIDE + kb;
        bp[ct][2] = XT + cc2 * XSTRIDE + kb;
    }

    const unsigned short* wp = ws + l15 * WSTRIDE + kb;   // global, L1-resident

    f32x4 acc[4][2];
#pragma unroll
    for (int ct = 0; ct < 4; ++ct) {
        acc[ct][0] = (f32x4){0.f, 0.f, 0.f, 0.f};
        acc[ct][1] = (f32x4){0.f, 0.f, 0.f, 0.f};
    }

#pragma unroll
    for (int c = 0; c < 12; ++c) {
        const int tap = c >> 2;
        const int ib  = (c & 3) * 32;
        bf16x8 A0 = *(const bf16x8*)(wp + c * 32);
        bf16x8 A1 = *(const bf16x8*)(wp + 16 * WSTRIDE + c * 32);
#pragma unroll
        for (int ct = 0; ct < 4; ++ct) {
            bf16x8 B = *(const bf16x8*)(bp[ct][tap] + ib);
            acc[ct][0] = __builtin_amdgcn_mfma_f32_16x16x32_bf16(A0, B, acc[ct][0], 0, 0, 0);
            acc[ct][1] = __builtin_amdgcn_mfma_f32_16x16x32_bf16(A1, B, acc[ct][1], 0, 0, 0);
        }
    }

    // ---- epilogue: C/D layout col=lane&15 (w), row=(lane>>4)*4+reg (j) ----
    {
        const int j0 = (lane >> 4) * 4;
        float* ob = out + (size_t)n * (C_OUT * HW) + (size_t)h * WW;
#pragma unroll
        for (int ct = 0; ct < 4; ++ct) {
            const int nn = ct * 16 + l15;
            if (nn < WW) {
#pragma unroll
                for (int r = 0; r < 4; ++r) {
                    ob[(size_t)(j0 + r) * HW + nn]      = acc[ct][0][r];
                    ob[(size_t)(j0 + r + 16) * HW + nn] = acc[ct][1][r];
                }
            }
        }
    }
}

extern "C" void kernel_launch(void* const* d_in, const int* in_sizes, int n_in,
                              void* d_out, int out_size, void* d_ws, size_t ws_size,
                              hipStream_t stream) {
    const float* x = (const float*)d_in[0];
    const float* w = (const float*)d_in[1];
    float* out = (float*)d_out;
    unsigned short* ws = (unsigned short*)d_ws;   // 32*392*2 = 25088 B needed

    pack_w_kernel<<<(C_OUT * WSTRIDE + 255) / 256, 256, 0, stream>>>(w, ws);
    conv_mfma_kernel<<<dim3(128 * HH), dim3(64), 0, stream>>>(x, ws, out);
}